// Round 1
// baseline (176.254 us; speedup 1.0000x reference)
//
#include <hip/hip_runtime.h>
#include <math.h>

// Problem constants (reference: S=256, B=2, HID=512, NH=8, HD=64, C=1)
constexpr int S_   = 256;
constexpr int B_   = 2;
constexpr int HID_ = 512;
constexpr int NH_  = 8;
constexpr int HD_  = 64;
constexpr int BSH  = B_ * S_ * HID_;   // 262144

__device__ __forceinline__ float artanh_c(float x) {
    // reference _artanh: clip to [-1+1e-7, 1-1e-7], then artanh
    x = fminf(fmaxf(x, -0.9999999f), 0.9999999f);
    return 0.5f * __logf((1.f + x) / (1.f - x));
}

__device__ __forceinline__ float wsum64(float v) {
    #pragma unroll
    for (int o = 1; o < 64; o <<= 1) v += __shfl_xor(v, o, 64);
    return v;
}

__device__ __forceinline__ float block_sum_256(float v, float* red) {
    const int t = threadIdx.x;
    __syncthreads();              // protect previous use of red
    red[t] = v;
    __syncthreads();
    #pragma unroll
    for (int sft = 128; sft > 0; sft >>= 1) {
        if (t < sft) red[t] += red[t + sft];
        __syncthreads();
    }
    return red[0];
}

// ---------------------------------------------------------------------------
// Stage 1a: mx = x @ W^T for all three weight matrices.
// RESTRUCTURED (was 32x32-tile/2x2-thread, ~4 B LDS per FMA -> LDS-pipe-bound):
//   * A (x rows) is wave-uniform: wave owns 8 rows; row pointers derived from
//     readfirstlane(wid) so A loads are scalar/uniform (SMEM path) — zero LDS.
//   * B (W cols) in LDS, [col][32kk] layout = direct copy of W rows (no
//     transpose), XOR-swizzled (idx ^ ((col&7)<<2)) so ds_read_b128 along kk
//     is conflict-free. Thread owns cols {lane, lane+64} (interleaved).
//   * Per 4kk per thread: 2 ds_read_b128 + 8 uniform loads feed 64 FMAs ->
//     LDS demand (4 waves x 2 x ~12cy = 96cy/CU) < VALU (128cy/SIMD): VALU-bound.
// Block = 32 rows x 128 cols (4 waves x 8 rows), grid 192 = 48 rowblk x 4 colblk.
// 32-row blocks never straddle a matrix boundary (512 % 32 == 0).
// ---------------------------------------------------------------------------
__global__ __launch_bounds__(256) void gemm3_kernel(
    const float* __restrict__ query,
    const float* __restrict__ Wq, const float* __restrict__ Wk,
    const float* __restrict__ Wv, float* __restrict__ ws_mx)
{
    const int tid  = threadIdx.x;
    const int lane = tid & 63;
    const int wv   = __builtin_amdgcn_readfirstlane(tid >> 6);   // wave id, SGPR
    const int rb   = blockIdx.x >> 2;            // 0..47  (32-row groups over 1536)
    const int cb   = (blockIdx.x & 3) * 128;     // col base 0/128/256/384
    const int which = (rb * 32) >> 9;            // uniform per block
    const float* __restrict__ W = (which == 0) ? Wq : (which == 1) ? Wk : Wv;

    // wave's 8 rows: which-relative row rr in [0,512), x row via (b*S+s) perm
    const int rloc = (rb * 32) & 511;
    const int wrow = rloc + wv * 8;
    const float* xr[8];
    #pragma unroll
    for (int i = 0; i < 8; ++i) {
        const int rr = wrow + i;
        xr[i] = query + (size_t)((rr & 255) * 2 + (rr >> 8)) * HID_;
    }

    __shared__ __align__(16) float sB[128 * 32];   // 16 KB, [col][kk] XOR-swizzled

    // staging: thread t handles col sc = t>>1, kk-half (t&1)*16 -> 4 float4
    const int sc = tid >> 1;
    const int sk = (tid & 1) * 16;
    const float* wp = W + (size_t)(cb + sc) * HID_ + sk;
    const int swz_st = (sc & 7) << 2;            // float-index XOR (16B granules)

    float acc[8][2] = {};
    float4 bvp[4];
    #pragma unroll
    for (int j = 0; j < 4; ++j) bvp[j] = *(const float4*)(wp + j * 4);

    for (int k0 = 0; k0 < HID_; k0 += 32) {
        __syncthreads();                         // previous chunk's reads done
        #pragma unroll
        for (int j = 0; j < 4; ++j)
            *(float4*)&sB[(sc * 32 + sk + j * 4) ^ swz_st] = bvp[j];
        __syncthreads();
        if (k0 + 32 < HID_) {                    // prefetch next chunk (in flight
            #pragma unroll                       //  across the compute phase)
            for (int j = 0; j < 4; ++j) bvp[j] = *(const float4*)(wp + k0 + 32 + j * 4);
        }
        #pragma unroll
        for (int kk = 0; kk < 32; kk += 4) {
            const int bidx = (lane * 32 + kk) ^ ((lane & 7) << 2);
            const float4 b0 = *(const float4*)&sB[bidx];          // col = lane
            const float4 b1 = *(const float4*)&sB[bidx + 2048];   // col = lane+64
            #pragma unroll
            for (int i = 0; i < 8; ++i) {
                const float4 a = *(const float4*)(xr[i] + k0 + kk);  // uniform
                acc[i][0] = fmaf(a.w, b0.w, fmaf(a.z, b0.z,
                            fmaf(a.y, b0.y, fmaf(a.x, b0.x, acc[i][0]))));
                acc[i][1] = fmaf(a.w, b1.w, fmaf(a.z, b1.z,
                            fmaf(a.y, b1.y, fmaf(a.x, b1.x, acc[i][1]))));
            }
        }
    }
    #pragma unroll
    for (int i = 0; i < 8; ++i) {
        const size_t gr = (size_t)(rb * 32 + wv * 8 + i);
        ws_mx[gr * HID_ + cb + lane]      = acc[i][0];
        ws_mx[gr * HID_ + cb + 64 + lane] = acc[i][1];
    }
}

// ---------------------------------------------------------------------------
// Stage 1b: per-row mobius epilogue, ONE WAVE PER ROW (no barriers).
// In-place: reads mx row from ws_qkv, writes q/k/v (logmap0+chunk expmap0).
// gamma stored in FLAT CHUNK ORDER: ws_gamma[(b*S+s)*NH + j] — identical to
// [b][h][n] flat indexing through the reshape identity (chunk c=s*8+j=h*256+n).
// ---------------------------------------------------------------------------
__global__ __launch_bounds__(256) void mobius_rows_kernel(
    const float* __restrict__ query,
    const float* __restrict__ bq, const float* __restrict__ bk,
    const float* __restrict__ bv,
    float* __restrict__ ws_qkv, float* __restrict__ ws_gamma)
{
    const int lane = threadIdx.x & 63;
    const int wv   = threadIdx.x >> 6;
    const int row  = blockIdx.x * 4 + wv;     // 0..1535
    const int which = row >> 9;
    const int rr    = row & 511;              // b*S + s
    const float* __restrict__ bias = (which == 0) ? bq : (which == 1) ? bk : bv;
    float* mrow = ws_qkv + (size_t)row * HID_;
    const float* xrow = query + (size_t)((rr & 255) * 2 + (rr >> 8)) * HID_;

    float m[8], x[8], bb[8];
    *(float4*)&m[0]  = ((const float4*)mrow)[lane * 2];
    *(float4*)&m[4]  = ((const float4*)mrow)[lane * 2 + 1];
    *(float4*)&x[0]  = ((const float4*)xrow)[lane * 2];
    *(float4*)&x[4]  = ((const float4*)xrow)[lane * 2 + 1];
    *(float4*)&bb[0] = ((const float4*)bias)[lane * 2];
    *(float4*)&bb[4] = ((const float4*)bias)[lane * 2 + 1];

    float x2p = 0.f, m2p = 0.f, b2p = 0.f;
    #pragma unroll
    for (int j = 0; j < 8; ++j) {
        x2p = fmaf(x[j], x[j], x2p);
        m2p = fmaf(m[j], m[j], m2p);
        b2p = fmaf(bb[j], bb[j], b2p);
    }
    const float x2s = wsum64(x2p);
    const float mn2 = wsum64(m2p);
    const float b2s = wsum64(b2p);
    const float xn = fmaxf(sqrtf(x2s), 1e-15f);
    const float mn = fmaxf(sqrtf(mn2), 1e-15f);
    // mobius_matvec: res = tanh(mn/xn * artanh(xn)) * mx/mn
    const float fac = tanhf(mn / xn * artanh_c(xn)) / mn;
    float r[8];
    float r2p = 0.f, ryp = 0.f;
    #pragma unroll
    for (int j = 0; j < 8; ++j) {
        r[j] = fac * m[j];
        r2p = fmaf(r[j], r[j], r2p);
        ryp = fmaf(r[j], bb[j], ryp);
    }
    const float r2s = wsum64(r2p);
    const float ry  = wsum64(ryp);
    // mobius_add(r, bias)
    const float a_c = 1.f + 2.f * ry + b2s;
    const float b_c = 1.f - r2s;
    const float den = 1.f + 2.f * ry + r2s * b2s;
    const float inv_den = 1.f / fmaxf(den, 1e-15f);
    float h[8];
    float h2p = 0.f;
    #pragma unroll
    for (int j = 0; j < 8; ++j) {
        h[j] = (a_c * r[j] + b_c * bb[j]) * inv_den;
        h2p = fmaf(h[j], h[j], h2p);
    }
    const float h2s = wsum64(h2p);
    float hn = fmaxf(sqrtf(h2s), 1e-15f);
    float pf = 1.f;
    if (hn > 0.996f) { pf = 0.996f / hn; hn = 0.996f; }   // projx
    const float lf = artanh_c(hn) / hn * pf;               // logmap0 (512-dim)
    float l[8];
    float l2p = 0.f;
    #pragma unroll
    for (int j = 0; j < 8; ++j) {
        l[j] = lf * h[j];
        l2p = fmaf(l[j], l[j], l2p);
    }
    // expmap0 over flat 64-chunks: chunk j = lanes j*8 .. j*8+7
    float cs = l2p;
    cs += __shfl_xor(cs, 1, 64);
    cs += __shfl_xor(cs, 2, 64);
    cs += __shfl_xor(cs, 4, 64);
    const float cn = fmaxf(sqrtf(cs), 1e-15f);
    const float th = tanhf(cn);
    const float sc = th / cn;
    float o[8];
    #pragma unroll
    for (int j = 0; j < 8; ++j) o[j] = sc * l[j];
    ((float4*)mrow)[lane * 2]     = *(float4*)&o[0];
    ((float4*)mrow)[lane * 2 + 1] = *(float4*)&o[4];
    if (which == 2 && (lane & 7) == 0) {
        const int j = lane >> 3;
        // gamma = 2 / max(1 - ||vl_chunk||^2, eps); ||vl_chunk|| = tanh(cn)
        ws_gamma[(size_t)rr * NH_ + j] = 2.f / fmaxf(1.f - th * th, 1e-15f);
    }
}

// ---------------------------------------------------------------------------
// Stage 2+3 FUSED: scores/probs + weighted gyro-midpoint + scalar_mul + logmap0.
// Block = (bh, 8-q tile), 512 blocks x 256 threads.
// Phase A: K staged in two 128-row LDS halves (XOR-swizzled); per-row |k|^2
//   precomputed during staging (k2 is q-independent — was computed 8x).
//   u-loop factored: u = a_c*(r_c*k - q), r_c = b_c/a_c (a_c>0 strictly since
//   |q|,|k|<1: a_c = (1-|k|)^2 + 2|k|(1-|q|·cos) > 0), so
//   sum 1/(u^2+c2) = (1/a_c^2) * sum 1/(w^2 + c2/a_c^2): 3 VALU + rcp per d.
// Phase B: wave w owns n in [64w,64w+64) for ALL 8 q (vl read once per block,
//   not 4x), partials combined via LDS.
// NOTE: lc must NOT alias ql (other blocks still read ql in phase A).
// ---------------------------------------------------------------------------
__global__ __launch_bounds__(256) void attn_kernel(
    const float* __restrict__ ws_qkv, const float* __restrict__ gamma,
    float* __restrict__ probs, float* __restrict__ lc)
{
    const int tid = threadIdx.x;
    const int bh  = blockIdx.x >> 5;
    const int q0  = (blockIdx.x & 31) * 8;
    const float* __restrict__ ql = ws_qkv + (size_t)bh * (S_ * HD_);
    const float* __restrict__ kl = ws_qkv + (size_t)BSH + (size_t)bh * (S_ * HD_);
    const float* __restrict__ vl = ws_qkv + (size_t)2 * BSH + (size_t)bh * (S_ * HD_);

    __shared__ __align__(16) float kS[128 * 64];   // 32 KB, swizzled
    __shared__ __align__(16) float qS[8 * 64];     // 2 KB
    __shared__ __align__(16) float pS[8 * 256];    // 8 KB: p*gamma, [q_local][n]
    __shared__ float gS[S_];                       // 1 KB
    __shared__ float k2S[128];                     // per-row |k|^2, per half
    __shared__ float nomP[4][8][64];               // 8 KB phase-B partials
    __shared__ float dnS[8];

    // gamma in flat-chunk order == [b][h][n] flat => contiguous at bh*S_
    gS[tid] = gamma[(size_t)bh * S_ + tid];
    if (tid < 128) ((float4*)qS)[tid] = ((const float4*)(ql + (size_t)q0 * 64))[tid];
    __syncthreads();

    const int q_l = tid >> 5;       // 0..7
    const int n_i = tid & 31;       // 0..31
    float qv[64];
    #pragma unroll
    for (int c = 0; c < 16; ++c)
        *(float4*)&qv[c * 4] = *(const float4*)&qS[q_l * 64 + c * 4];
    float q2 = 0.f;
    #pragma unroll
    for (int d = 0; d < 64; ++d) q2 = fmaf(qv[d], qv[d], q2);
    const float b_c = 1.f - q2;
    float* __restrict__ prow = probs + ((size_t)(bh * S_ + q0 + q_l)) * S_;

    const int c4 = tid & 15;        // staging: chunk
    const int nb = tid >> 4;        // staging: row base
    float sp = 0.f, spg = 0.f;

    for (int half = 0; half < 2; ++half) {
        __syncthreads();            // protect kS/k2S reuse across halves
        #pragma unroll
        for (int jj = 0; jj < 8; ++jj) {
            const int n = nb + 16 * jj;   // 0..127
            const float4 v = *(const float4*)(kl + ((size_t)(half * 128 + n)) * 64 + c4 * 4);
            *(float4*)&kS[n * 64 + ((c4 ^ (n & 15)) * 4)] = v;
            // per-row |k|^2: reduce 16 chunk-partials over the 16 lanes sharing nb
            float pk = fmaf(v.x, v.x, fmaf(v.y, v.y, fmaf(v.z, v.z, v.w * v.w)));
            pk += __shfl_xor(pk, 1, 64);
            pk += __shfl_xor(pk, 2, 64);
            pk += __shfl_xor(pk, 4, 64);
            pk += __shfl_xor(pk, 8, 64);
            if (c4 == 0) k2S[n] = pk;
        }
        __syncthreads();
        #pragma unroll
        for (int j = 0; j < 4; ++j) {
            const int n = n_i + 32 * j;   // within half
            float kv[64];
            #pragma unroll
            for (int c = 0; c < 16; ++c)
                *(float4*)&kv[c * 4] = *(const float4*)&kS[n * 64 + ((c ^ (n & 15)) * 4)];
            float s = 0.f;
            #pragma unroll
            for (int d = 0; d < 64; ++d) s = fmaf(qv[d], kv[d], s);
            const float k2  = k2S[n];
            const float a_c = 1.f - 2.f * s + k2;
            const float den = fmaxf(fmaf(q2, k2, 1.f - 2.f * s), 1e-15f);
            const float ra  = __builtin_amdgcn_rcpf(a_c);
            const float r_c = b_c * ra;
            const float scale = den * den * ra * ra;   // den^2 / a_c^2
            const float c2  = 1e-30f * scale;
            float invsum = 0.f;
            #pragma unroll
            for (int d = 0; d < 64; ++d) {
                const float w = fmaf(r_c, kv[d], -qv[d]);
                invsum += __builtin_amdgcn_rcpf(fmaf(w, w, c2));
            }
            const float t1 = __builtin_amdgcn_rsqf(scale * invsum);
            const float p = 0.5f - 0.5f * fminf(t1, 0.9999999f);
            const int gn = half * 128 + n;
            prow[gn] = p;
            const float g = gS[gn];
            pS[q_l * 256 + gn] = p * g;
            sp += p; spg += p * g;
        }
    }
    // reduce sp/spg over the 32 threads sharing q_l (lanes [0,32) / [32,64))
    #pragma unroll
    for (int o = 1; o < 32; o <<= 1) {
        sp  += __shfl_xor(sp, o, 64);
        spg += __shfl_xor(spg, o, 64);
    }
    if ((tid & 31) == 0) dnS[q_l] = spg - sp;   // denom = sum p*(g-1)
    __syncthreads();

    // Phase B: wave w owns n in [64w, 64w+64), all 8 q; lane = d
    const int w = tid >> 6, d = tid & 63;
    float acc[8] = {};
    const float* __restrict__ vbase = vl + (size_t)(w * 64) * 64;
    #pragma unroll 4
    for (int i4 = 0; i4 < 16; ++i4) {
        float vv[4];
        #pragma unroll
        for (int j2 = 0; j2 < 4; ++j2) vv[j2] = vbase[(size_t)(i4 * 4 + j2) * 64 + d];
        #pragma unroll
        for (int qq = 0; qq < 8; ++qq) {
            const float4 pq = *(const float4*)&pS[qq * 256 + w * 64 + i4 * 4]; // broadcast
            acc[qq] = fmaf(pq.x, vv[0], acc[qq]);
            acc[qq] = fmaf(pq.y, vv[1], acc[qq]);
            acc[qq] = fmaf(pq.z, vv[2], acc[qq]);
            acc[qq] = fmaf(pq.w, vv[3], acc[qq]);
        }
    }
    #pragma unroll
    for (int qq = 0; qq < 8; ++qq) nomP[w][qq][d] = acc[qq];
    __syncthreads();

    #pragma unroll
    for (int t = 0; t < 2; ++t) {
        const int qq = (tid >> 6) + 4 * t;
        const float nom = nomP[0][qq][d] + nomP[1][qq][d] + nomP[2][qq][d] + nomP[3][qq][d];
        const float dd = dnS[qq];
        const float adn = fmaxf(fabsf(dd), 1e-10f);
        const float sden = (dd >= 0.f) ? adn : -adn;
        const float m = nom / sden;
        const float ss = wsum64(m * m);
        const float nn = fmaxf(sqrtf(ss), 1e-15f);
        const float s1 = tanhf(0.5f * artanh_c(nn));     // mobius_scalar_mul(0.5)
        const float res = s1 * m / nn;
        const float nres = fmaxf(s1, 1e-15f);            // ||res|| = s1 >= 0
        lc[((size_t)(bh * S_ + q0 + qq)) * HD_ + d] = (artanh_c(nres) / nres) * res;
    }
}

// ---------------------------------------------------------------------------
// Stage 4: gather heads -> [B,Q,512] row, expmap0 over 512, store [S,B,HID].
// ---------------------------------------------------------------------------
__global__ __launch_bounds__(256) void outproj_kernel(
    const float* __restrict__ lc, float* __restrict__ out0)
{
    const int t = threadIdx.x;
    const int s = blockIdx.x & (S_ - 1);
    const int b = blockIdx.x >> 8;
    __shared__ float red[256];
    const int h0 = t >> 6, d0 = t & 63;
    const int e1 = t + 256;
    const int h1 = e1 >> 6, d1 = e1 & 63;
    const float v0 = lc[(((size_t)(b * NH_ + h0)) * S_ + s) * HD_ + d0];
    const float v1 = lc[(((size_t)(b * NH_ + h1)) * S_ + s) * HD_ + d1];
    const float ss = block_sum_256(v0 * v0 + v1 * v1, red);
    const float nn = fmaxf(sqrtf(ss), 1e-15f);
    const float f = tanhf(nn) / nn;
    float* orow = out0 + ((size_t)(s * B_ + b)) * HID_;
    orow[t] = f * v0;
    orow[t + 256] = f * v1;
}

extern "C" void kernel_launch(void* const* d_in, const int* in_sizes, int n_in,
                              void* d_out, int out_size, void* d_ws, size_t ws_size,
                              hipStream_t stream) {
    (void)in_sizes; (void)n_in; (void)out_size; (void)ws_size;
    const float* query = (const float*)d_in[0];
    const float* Wq = (const float*)d_in[1];
    const float* bq = (const float*)d_in[2];
    const float* Wk = (const float*)d_in[3];
    const float* bk = (const float*)d_in[4];
    const float* Wv = (const float*)d_in[5];
    const float* bv = (const float*)d_in[6];

    float* out0  = (float*)d_out;                          // [S,B,HID] = 262144
    float* probs = out0 + (size_t)S_ * B_ * HID_;          // [B,NH,S,S] = 1048576

    float* ws       = (float*)d_ws;
    float* ws_qkv   = ws;                                  // mx -> ql|kl|vl : 3*262144 floats
    float* ws_gamma = ws + (size_t)3 * BSH;                // 4096 floats, flat chunk order
    float* ws_lc    = ws + (size_t)3 * BSH + 4096;         // 131072 floats (NO alias: attn
                                                           // writes lc while other blocks read ql)

    gemm3_kernel<<<dim3(192), dim3(256), 0, stream>>>(query, Wq, Wk, Wv, ws_qkv);
    mobius_rows_kernel<<<dim3(384), dim3(256), 0, stream>>>(query, bq, bk, bv, ws_qkv, ws_gamma);
    attn_kernel<<<dim3(512), dim3(256), 0, stream>>>(ws_qkv, ws_gamma, probs, ws_lc);
    outproj_kernel<<<dim3(B_ * S_), dim3(256), 0, stream>>>(ws_lc, out0);
}

// Round 2
// 123.381 us; speedup vs baseline: 1.4285x; 1.4285x over previous
//
#include <hip/hip_runtime.h>
#include <math.h>

// Problem constants (reference: S=256, B=2, HID=512, NH=8, HD=64, C=1)
constexpr int S_   = 256;
constexpr int B_   = 2;
constexpr int HID_ = 512;
constexpr int NH_  = 8;
constexpr int HD_  = 64;
constexpr int BSH  = B_ * S_ * HID_;   // 262144

__device__ __forceinline__ float artanh_c(float x) {
    // reference _artanh: clip to [-1+1e-7, 1-1e-7], then artanh
    x = fminf(fmaxf(x, -0.9999999f), 0.9999999f);
    return 0.5f * __logf((1.f + x) / (1.f - x));
}

__device__ __forceinline__ float wsum64(float v) {
    #pragma unroll
    for (int o = 1; o < 64; o <<= 1) v += __shfl_xor(v, o, 64);
    return v;
}

__device__ __forceinline__ float block_sum_256(float v, float* red) {
    const int t = threadIdx.x;
    __syncthreads();              // protect previous use of red
    red[t] = v;
    __syncthreads();
    #pragma unroll
    for (int sft = 128; sft > 0; sft >>= 1) {
        if (t < sft) red[t] += red[t + sft];
        __syncthreads();
    }
    return red[0];
}

// ---------------------------------------------------------------------------
// Stage 1a: mx = x @ W^T for all three weight matrices.
// v3 (post-mortem of v2's latency disaster: 192 blocks x scalar global loads
// in the inner loop = 6% VALUBusy). Back to all-operands-in-LDS (latency
// hidden by chunk staging + prefetch), but with 4x less LDS traffic per FMA
// than v1 (round-0):
//   * Block 64x64, 4 waves; wave tile 16 rows x 64 cols; thread tile 4x4.
//   * Per kk per thread: ONE ds_read_b128 of A (4 distinct addrs per wave ->
//     broadcast) + ONE ds_read_b128 of B (16 addrs, pad 68 keeps 16B-aligned
//     and conflict-free) feeding 16 FMAs. v1 paid 2x ds_read_b64 per 4 FMAs.
//   * LDS per CU per kk ~40 cy vs VALU 32 cy/SIMD -> near-balanced.
//   * Staging identical in style to v1 (float4 global load, 4x b32 transposed
//     writes, next-chunk prefetch overlapped with compute).
// Grid 24 rowblk x 8 colblk = 192 blocks; 64-row blocks never straddle a
// matrix boundary (512 % 64 == 0). Predicted ~12-15 us.
// ---------------------------------------------------------------------------
__global__ __launch_bounds__(256) void gemm3_kernel(
    const float* __restrict__ query,
    const float* __restrict__ Wq, const float* __restrict__ Wk,
    const float* __restrict__ Wv, float* __restrict__ ws_mx)
{
    const int tid  = threadIdx.x;
    const int lane = tid & 63;
    const int wv   = tid >> 6;
    const int row0 = (blockIdx.x >> 3) * 64;     // 0..1472 over 1536 rows
    const int col0 = (blockIdx.x & 7) * 64;      // 0..448
    const int which = row0 >> 9;
    const int rloc  = row0 & 511;                // which-relative row base
    const float* __restrict__ W = (which == 0) ? Wq : (which == 1) ? Wk : Wv;

    __shared__ __align__(16) float sA[32][68];   // [kk][row], pad 68 (16B-aligned rows)
    __shared__ __align__(16) float sB[32][68];   // [kk][col]

    // staging: thread -> (row/col rs, k-quad ks); 8 lanes = 128B contiguous
    const int rs = tid >> 3;          // 0..31
    const int ks = (tid & 7) * 4;     // 0,4,...,28
    const int ra0 = rloc + rs, ra1 = rloc + rs + 32;
    const float* pa0 = query + (size_t)((ra0 & 255) * 2 + (ra0 >> 8)) * HID_ + ks;
    const float* pa1 = query + (size_t)((ra1 & 255) * 2 + (ra1 >> 8)) * HID_ + ks;
    const float* pb0 = W + (size_t)(col0 + rs) * HID_ + ks;
    const float* pb1 = W + (size_t)(col0 + rs + 32) * HID_ + ks;

    // compute: wave wv rows [wv*16, wv*16+16), lane g=row-quad, c=col-quad
    const int g = lane >> 4;          // 0..3
    const int c = lane & 15;          // 0..15
    const int arow = wv * 16 + g * 4;
    const int bcol = c * 4;

    float acc[4][4] = {};
    float4 va0 = *(const float4*)pa0;
    float4 va1 = *(const float4*)pa1;
    float4 vb0 = *(const float4*)pb0;
    float4 vb1 = *(const float4*)pb1;

    for (int k0 = 0; k0 < HID_; k0 += 32) {
        __syncthreads();                         // previous chunk's reads done
        #pragma unroll
        for (int j = 0; j < 4; ++j) {
            sA[ks + j][rs]      = ((const float*)&va0)[j];
            sA[ks + j][rs + 32] = ((const float*)&va1)[j];
            sB[ks + j][rs]      = ((const float*)&vb0)[j];
            sB[ks + j][rs + 32] = ((const float*)&vb1)[j];
        }
        __syncthreads();
        if (k0 + 32 < HID_) {                    // prefetch next chunk; completes
            va0 = *(const float4*)(pa0 + k0 + 32);   // under the 32-kk compute
            va1 = *(const float4*)(pa1 + k0 + 32);
            vb0 = *(const float4*)(pb0 + k0 + 32);
            vb1 = *(const float4*)(pb1 + k0 + 32);
        }
        #pragma unroll
        for (int kk = 0; kk < 32; ++kk) {
            float ar[4], br[4];
            *(float4*)ar = *(const float4*)&sA[kk][arow];   // 4-addr broadcast
            *(float4*)br = *(const float4*)&sB[kk][bcol];   // 16-addr, conflict-free
            #pragma unroll
            for (int i = 0; i < 4; ++i)
                #pragma unroll
                for (int j = 0; j < 4; ++j)
                    acc[i][j] = fmaf(ar[i], br[j], acc[i][j]);
        }
    }
    #pragma unroll
    for (int i = 0; i < 4; ++i) {
        *(float4*)&ws_mx[(size_t)(row0 + arow + i) * HID_ + col0 + bcol] =
            make_float4(acc[i][0], acc[i][1], acc[i][2], acc[i][3]);
    }
}

// ---------------------------------------------------------------------------
// Stage 1b: per-row mobius epilogue, ONE WAVE PER ROW (no barriers).
// In-place: reads mx row from ws_qkv, writes q/k/v (logmap0+chunk expmap0).
// gamma stored in FLAT CHUNK ORDER: ws_gamma[(b*S+s)*NH + j] — identical to
// [b][h][n] flat indexing through the reshape identity (chunk c=s*8+j=h*256+n).
// ---------------------------------------------------------------------------
__global__ __launch_bounds__(256) void mobius_rows_kernel(
    const float* __restrict__ query,
    const float* __restrict__ bq, const float* __restrict__ bk,
    const float* __restrict__ bv,
    float* __restrict__ ws_qkv, float* __restrict__ ws_gamma)
{
    const int lane = threadIdx.x & 63;
    const int wv   = threadIdx.x >> 6;
    const int row  = blockIdx.x * 4 + wv;     // 0..1535
    const int which = row >> 9;
    const int rr    = row & 511;              // b*S + s
    const float* __restrict__ bias = (which == 0) ? bq : (which == 1) ? bk : bv;
    float* mrow = ws_qkv + (size_t)row * HID_;
    const float* xrow = query + (size_t)((rr & 255) * 2 + (rr >> 8)) * HID_;

    float m[8], x[8], bb[8];
    *(float4*)&m[0]  = ((const float4*)mrow)[lane * 2];
    *(float4*)&m[4]  = ((const float4*)mrow)[lane * 2 + 1];
    *(float4*)&x[0]  = ((const float4*)xrow)[lane * 2];
    *(float4*)&x[4]  = ((const float4*)xrow)[lane * 2 + 1];
    *(float4*)&bb[0] = ((const float4*)bias)[lane * 2];
    *(float4*)&bb[4] = ((const float4*)bias)[lane * 2 + 1];

    float x2p = 0.f, m2p = 0.f, b2p = 0.f;
    #pragma unroll
    for (int j = 0; j < 8; ++j) {
        x2p = fmaf(x[j], x[j], x2p);
        m2p = fmaf(m[j], m[j], m2p);
        b2p = fmaf(bb[j], bb[j], b2p);
    }
    const float x2s = wsum64(x2p);
    const float mn2 = wsum64(m2p);
    const float b2s = wsum64(b2p);
    const float xn = fmaxf(sqrtf(x2s), 1e-15f);
    const float mn = fmaxf(sqrtf(mn2), 1e-15f);
    // mobius_matvec: res = tanh(mn/xn * artanh(xn)) * mx/mn
    const float fac = tanhf(mn / xn * artanh_c(xn)) / mn;
    float r[8];
    float r2p = 0.f, ryp = 0.f;
    #pragma unroll
    for (int j = 0; j < 8; ++j) {
        r[j] = fac * m[j];
        r2p = fmaf(r[j], r[j], r2p);
        ryp = fmaf(r[j], bb[j], ryp);
    }
    const float r2s = wsum64(r2p);
    const float ry  = wsum64(ryp);
    // mobius_add(r, bias)
    const float a_c = 1.f + 2.f * ry + b2s;
    const float b_c = 1.f - r2s;
    const float den = 1.f + 2.f * ry + r2s * b2s;
    const float inv_den = 1.f / fmaxf(den, 1e-15f);
    float h[8];
    float h2p = 0.f;
    #pragma unroll
    for (int j = 0; j < 8; ++j) {
        h[j] = (a_c * r[j] + b_c * bb[j]) * inv_den;
        h2p = fmaf(h[j], h[j], h2p);
    }
    const float h2s = wsum64(h2p);
    float hn = fmaxf(sqrtf(h2s), 1e-15f);
    float pf = 1.f;
    if (hn > 0.996f) { pf = 0.996f / hn; hn = 0.996f; }   // projx
    const float lf = artanh_c(hn) / hn * pf;               // logmap0 (512-dim)
    float l[8];
    float l2p = 0.f;
    #pragma unroll
    for (int j = 0; j < 8; ++j) {
        l[j] = lf * h[j];
        l2p = fmaf(l[j], l[j], l2p);
    }
    // expmap0 over flat 64-chunks: chunk j = lanes j*8 .. j*8+7
    float cs = l2p;
    cs += __shfl_xor(cs, 1, 64);
    cs += __shfl_xor(cs, 2, 64);
    cs += __shfl_xor(cs, 4, 64);
    const float cn = fmaxf(sqrtf(cs), 1e-15f);
    const float th = tanhf(cn);
    const float sc = th / cn;
    float o[8];
    #pragma unroll
    for (int j = 0; j < 8; ++j) o[j] = sc * l[j];
    ((float4*)mrow)[lane * 2]     = *(float4*)&o[0];
    ((float4*)mrow)[lane * 2 + 1] = *(float4*)&o[4];
    if (which == 2 && (lane & 7) == 0) {
        const int j = lane >> 3;
        // gamma = 2 / max(1 - ||vl_chunk||^2, eps); ||vl_chunk|| = tanh(cn)
        ws_gamma[(size_t)rr * NH_ + j] = 2.f / fmaxf(1.f - th * th, 1e-15f);
    }
}

// ---------------------------------------------------------------------------
// Stage 2+3 FUSED: scores/probs + weighted gyro-midpoint + scalar_mul + logmap0.
// Block = (bh, 8-q tile), 512 blocks x 256 threads.
// Phase A: K staged in two 128-row LDS halves (XOR-swizzled); per-row |k|^2
//   precomputed during staging (k2 is q-independent — was computed 8x).
//   u-loop factored: u = a_c*(r_c*k - q), r_c = b_c/a_c (a_c>0 strictly since
//   |q|,|k|<1: a_c = (1-|k|)^2 + 2|k|(1-|q|·cos) > 0), so
//   sum 1/(u^2+c2) = (1/a_c^2) * sum 1/(w^2 + c2/a_c^2): 3 VALU + rcp per d.
// Phase B: wave w owns n in [64w,64w+64) for ALL 8 q (vl read once per block,
//   not 4x), partials combined via LDS.
// NOTE: lc must NOT alias ql (other blocks still read ql in phase A).
// ---------------------------------------------------------------------------
__global__ __launch_bounds__(256) void attn_kernel(
    const float* __restrict__ ws_qkv, const float* __restrict__ gamma,
    float* __restrict__ probs, float* __restrict__ lc)
{
    const int tid = threadIdx.x;
    const int bh  = blockIdx.x >> 5;
    const int q0  = (blockIdx.x & 31) * 8;
    const float* __restrict__ ql = ws_qkv + (size_t)bh * (S_ * HD_);
    const float* __restrict__ kl = ws_qkv + (size_t)BSH + (size_t)bh * (S_ * HD_);
    const float* __restrict__ vl = ws_qkv + (size_t)2 * BSH + (size_t)bh * (S_ * HD_);

    __shared__ __align__(16) float kS[128 * 64];   // 32 KB, swizzled
    __shared__ __align__(16) float qS[8 * 64];     // 2 KB
    __shared__ __align__(16) float pS[8 * 256];    // 8 KB: p*gamma, [q_local][n]
    __shared__ float gS[S_];                       // 1 KB
    __shared__ float k2S[128];                     // per-row |k|^2, per half
    __shared__ float nomP[4][8][64];               // 8 KB phase-B partials
    __shared__ float dnS[8];

    // gamma in flat-chunk order == [b][h][n] flat => contiguous at bh*S_
    gS[tid] = gamma[(size_t)bh * S_ + tid];
    if (tid < 128) ((float4*)qS)[tid] = ((const float4*)(ql + (size_t)q0 * 64))[tid];
    __syncthreads();

    const int q_l = tid >> 5;       // 0..7
    const int n_i = tid & 31;       // 0..31
    float qv[64];
    #pragma unroll
    for (int c = 0; c < 16; ++c)
        *(float4*)&qv[c * 4] = *(const float4*)&qS[q_l * 64 + c * 4];
    float q2 = 0.f;
    #pragma unroll
    for (int d = 0; d < 64; ++d) q2 = fmaf(qv[d], qv[d], q2);
    const float b_c = 1.f - q2;
    float* __restrict__ prow = probs + ((size_t)(bh * S_ + q0 + q_l)) * S_;

    const int c4 = tid & 15;        // staging: chunk
    const int nb = tid >> 4;        // staging: row base
    float sp = 0.f, spg = 0.f;

    for (int half = 0; half < 2; ++half) {
        __syncthreads();            // protect kS/k2S reuse across halves
        #pragma unroll
        for (int jj = 0; jj < 8; ++jj) {
            const int n = nb + 16 * jj;   // 0..127
            const float4 v = *(const float4*)(kl + ((size_t)(half * 128 + n)) * 64 + c4 * 4);
            *(float4*)&kS[n * 64 + ((c4 ^ (n & 15)) * 4)] = v;
            // per-row |k|^2: reduce 16 chunk-partials over the 16 lanes sharing nb
            float pk = fmaf(v.x, v.x, fmaf(v.y, v.y, fmaf(v.z, v.z, v.w * v.w)));
            pk += __shfl_xor(pk, 1, 64);
            pk += __shfl_xor(pk, 2, 64);
            pk += __shfl_xor(pk, 4, 64);
            pk += __shfl_xor(pk, 8, 64);
            if (c4 == 0) k2S[n] = pk;
        }
        __syncthreads();
        #pragma unroll
        for (int j = 0; j < 4; ++j) {
            const int n = n_i + 32 * j;   // within half
            float kv[64];
            #pragma unroll
            for (int c = 0; c < 16; ++c)
                *(float4*)&kv[c * 4] = *(const float4*)&kS[n * 64 + ((c ^ (n & 15)) * 4)];
            float s = 0.f;
            #pragma unroll
            for (int d = 0; d < 64; ++d) s = fmaf(qv[d], kv[d], s);
            const float k2  = k2S[n];
            const float a_c = 1.f - 2.f * s + k2;
            const float den = fmaxf(fmaf(q2, k2, 1.f - 2.f * s), 1e-15f);
            const float ra  = __builtin_amdgcn_rcpf(a_c);
            const float r_c = b_c * ra;
            const float scale = den * den * ra * ra;   // den^2 / a_c^2
            const float c2  = 1e-30f * scale;
            float invsum = 0.f;
            #pragma unroll
            for (int d = 0; d < 64; ++d) {
                const float w = fmaf(r_c, kv[d], -qv[d]);
                invsum += __builtin_amdgcn_rcpf(fmaf(w, w, c2));
            }
            const float t1 = __builtin_amdgcn_rsqf(scale * invsum);
            const float p = 0.5f - 0.5f * fminf(t1, 0.9999999f);
            const int gn = half * 128 + n;
            prow[gn] = p;
            const float g = gS[gn];
            pS[q_l * 256 + gn] = p * g;
            sp += p; spg += p * g;
        }
    }
    // reduce sp/spg over the 32 threads sharing q_l (lanes [0,32) / [32,64))
    #pragma unroll
    for (int o = 1; o < 32; o <<= 1) {
        sp  += __shfl_xor(sp, o, 64);
        spg += __shfl_xor(spg, o, 64);
    }
    if ((tid & 31) == 0) dnS[q_l] = spg - sp;   // denom = sum p*(g-1)
    __syncthreads();

    // Phase B: wave w owns n in [64w, 64w+64), all 8 q; lane = d
    const int w = tid >> 6, d = tid & 63;
    float acc[8] = {};
    const float* __restrict__ vbase = vl + (size_t)(w * 64) * 64;
    #pragma unroll 4
    for (int i4 = 0; i4 < 16; ++i4) {
        float vv[4];
        #pragma unroll
        for (int j2 = 0; j2 < 4; ++j2) vv[j2] = vbase[(size_t)(i4 * 4 + j2) * 64 + d];
        #pragma unroll
        for (int qq = 0; qq < 8; ++qq) {
            const float4 pq = *(const float4*)&pS[qq * 256 + w * 64 + i4 * 4]; // broadcast
            acc[qq] = fmaf(pq.x, vv[0], acc[qq]);
            acc[qq] = fmaf(pq.y, vv[1], acc[qq]);
            acc[qq] = fmaf(pq.z, vv[2], acc[qq]);
            acc[qq] = fmaf(pq.w, vv[3], acc[qq]);
        }
    }
    #pragma unroll
    for (int qq = 0; qq < 8; ++qq) nomP[w][qq][d] = acc[qq];
    __syncthreads();

    #pragma unroll
    for (int t = 0; t < 2; ++t) {
        const int qq = (tid >> 6) + 4 * t;
        const float nom = nomP[0][qq][d] + nomP[1][qq][d] + nomP[2][qq][d] + nomP[3][qq][d];
        const float dd = dnS[qq];
        const float adn = fmaxf(fabsf(dd), 1e-10f);
        const float sden = (dd >= 0.f) ? adn : -adn;
        const float m = nom / sden;
        const float ss = wsum64(m * m);
        const float nn = fmaxf(sqrtf(ss), 1e-15f);
        const float s1 = tanhf(0.5f * artanh_c(nn));     // mobius_scalar_mul(0.5)
        const float res = s1 * m / nn;
        const float nres = fmaxf(s1, 1e-15f);            // ||res|| = s1 >= 0
        lc[((size_t)(bh * S_ + q0 + qq)) * HD_ + d] = (artanh_c(nres) / nres) * res;
    }
}

// ---------------------------------------------------------------------------
// Stage 4: gather heads -> [B,Q,512] row, expmap0 over 512, store [S,B,HID].
// ---------------------------------------------------------------------------
__global__ __launch_bounds__(256) void outproj_kernel(
    const float* __restrict__ lc, float* __restrict__ out0)
{
    const int t = threadIdx.x;
    const int s = blockIdx.x & (S_ - 1);
    const int b = blockIdx.x >> 8;
    __shared__ float red[256];
    const int h0 = t >> 6, d0 = t & 63;
    const int e1 = t + 256;
    const int h1 = e1 >> 6, d1 = e1 & 63;
    const float v0 = lc[(((size_t)(b * NH_ + h0)) * S_ + s) * HD_ + d0];
    const float v1 = lc[(((size_t)(b * NH_ + h1)) * S_ + s) * HD_ + d1];
    const float ss = block_sum_256(v0 * v0 + v1 * v1, red);
    const float nn = fmaxf(sqrtf(ss), 1e-15f);
    const float f = tanhf(nn) / nn;
    float* orow = out0 + ((size_t)(s * B_ + b)) * HID_;
    orow[t] = f * v0;
    orow[t + 256] = f * v1;
}

extern "C" void kernel_launch(void* const* d_in, const int* in_sizes, int n_in,
                              void* d_out, int out_size, void* d_ws, size_t ws_size,
                              hipStream_t stream) {
    (void)in_sizes; (void)n_in; (void)out_size; (void)ws_size;
    const float* query = (const float*)d_in[0];
    const float* Wq = (const float*)d_in[1];
    const float* bq = (const float*)d_in[2];
    const float* Wk = (const float*)d_in[3];
    const float* bk = (const float*)d_in[4];
    const float* Wv = (const float*)d_in[5];
    const float* bv = (const float*)d_in[6];

    float* out0  = (float*)d_out;                          // [S,B,HID] = 262144
    float* probs = out0 + (size_t)S_ * B_ * HID_;          // [B,NH,S,S] = 1048576

    float* ws       = (float*)d_ws;
    float* ws_qkv   = ws;                                  // mx -> ql|kl|vl : 3*262144 floats
    float* ws_gamma = ws + (size_t)3 * BSH;                // 4096 floats, flat chunk order
    float* ws_lc    = ws + (size_t)3 * BSH + 4096;         // 131072 floats (NO alias: attn
                                                           // writes lc while other blocks read ql)

    gemm3_kernel<<<dim3(192), dim3(256), 0, stream>>>(query, Wq, Wk, Wv, ws_qkv);
    mobius_rows_kernel<<<dim3(384), dim3(256), 0, stream>>>(query, bq, bk, bv, ws_qkv, ws_gamma);
    attn_kernel<<<dim3(512), dim3(256), 0, stream>>>(ws_qkv, ws_gamma, probs, ws_lc);
    outproj_kernel<<<dim3(B_ * S_), dim3(256), 0, stream>>>(ws_lc, out0);
}

// Round 3
// 110.714 us; speedup vs baseline: 1.5920x; 1.1144x over previous
//
#include <hip/hip_runtime.h>
#include <math.h>

// Problem constants (reference: S=256, B=2, HID=512, NH=8, HD=64, C=1)
constexpr int S_   = 256;
constexpr int B_   = 2;
constexpr int HID_ = 512;
constexpr int NH_  = 8;
constexpr int HD_  = 64;
constexpr int BSH  = B_ * S_ * HID_;   // 262144

typedef unsigned short u16;
typedef short s16x8 __attribute__((ext_vector_type(8)));
typedef float f32x4 __attribute__((ext_vector_type(4)));

__device__ __forceinline__ float artanh_c(float x) {
    // reference _artanh: clip to [-1+1e-7, 1-1e-7], then artanh
    x = fminf(fmaxf(x, -0.9999999f), 0.9999999f);
    return 0.5f * __logf((1.f + x) / (1.f - x));
}

__device__ __forceinline__ float wsum64(float v) {
    #pragma unroll
    for (int o = 1; o < 64; o <<= 1) v += __shfl_xor(v, o, 64);
    return v;
}

__device__ __forceinline__ float block_sum_256(float v, float* red) {
    const int t = threadIdx.x;
    __syncthreads();              // protect previous use of red
    red[t] = v;
    __syncthreads();
    #pragma unroll
    for (int sft = 128; sft > 0; sft >>= 1) {
        if (t < sft) red[t] += red[t + sft];
        __syncthreads();
    }
    return red[0];
}

// ---------------------------------------------------------------------------
// Stage 0: fp32 -> bf16 hi/lo split (exact: a = hi + lo + O(2^-16 a)).
// Rows 0..511   = X (query rows in gemm order rr -> query row (rr&255)*2+(rr>>8))
// Rows 512..2047 = Wq|Wk|Wv stacked (B^T operand: row = output col).
// One wave per row; lane handles 8 consecutive elems (fully coalesced 16B).
// ---------------------------------------------------------------------------
__global__ __launch_bounds__(256) void cvt_kernel(
    const float* __restrict__ query, const float* __restrict__ Wq,
    const float* __restrict__ Wk, const float* __restrict__ Wv,
    u16* __restrict__ Ahi, u16* __restrict__ Alo,
    u16* __restrict__ Bhi, u16* __restrict__ Blo)
{
    const int lane = threadIdx.x & 63;
    const int gr = blockIdx.x * 4 + (threadIdx.x >> 6);   // 0..2047
    const float* src;
    u16 *dh, *dl;
    if (gr < 512) {
        src = query + (size_t)((gr & 255) * 2 + (gr >> 8)) * HID_;
        dh = Ahi + (size_t)gr * HID_;
        dl = Alo + (size_t)gr * HID_;
    } else {
        const int m = gr - 512;
        const float* __restrict__ W = ((m >> 9) == 0) ? Wq : ((m >> 9) == 1) ? Wk : Wv;
        src = W + (size_t)(m & 511) * HID_;
        dh = Bhi + (size_t)m * HID_;
        dl = Blo + (size_t)m * HID_;
    }
    float v[8];
    *(float4*)&v[0] = *(const float4*)(src + lane * 8);
    *(float4*)&v[4] = *(const float4*)(src + lane * 8 + 4);
    s16x8 hv, lv;
    #pragma unroll
    for (int j = 0; j < 8; ++j) {
        const unsigned u = __float_as_uint(v[j]);
        const float hf = __uint_as_float(u & 0xFFFF0000u);
        hv[j] = (short)(u >> 16);
        lv[j] = (short)(__float_as_uint(v[j] - hf) >> 16);   // exact residual, trunc
    }
    *(s16x8*)(dh + lane * 8) = hv;
    *(s16x8*)(dl + lane * 8) = lv;
}

// ---------------------------------------------------------------------------
// Stage 1a: mx = x @ W^T via bf16 MFMA with hi/lo error compensation:
//   C = Ahi*Bhi^T + Ahi*Blo^T + Alo*Bhi^T   (fp32 accumulate; dropped Alo*Blo
//   term ~2^-16 relative -> ~1e-7 abs on mx, far under the absmax budget).
// v4 (post-mortem v3: ~43 us, LDS-pipe + occupancy bound on the VALU path).
// MFMA pipe is otherwise idle; per-FLOP LDS traffic drops 16x.
//   Block 64x64 tile, 4 waves; wave 32x32 = 2x2 frags of 16x16x32.
//   Per K32-step per wave: 8 swizzled ds_read_b128 + 12 MFMA.
//   Frag layouts (mfma_f32_16x16x32_bf16): A row=lane&15, k=(lane>>4)*8+j;
//   B col=lane&15 (B^T rows K-contiguous -> same 16B-slice read as A);
//   C/D col=lane&15, row=(lane>>4)*4+reg  [learn_hip m89/m91 verified].
//   LDS: 4 arrays [64 rows][4 x 16B k-slices], slice ^= (row>>1)&3 -> frag
//   reads land 2 lanes/bank (free).
// Grid 24 rowblk x 8 colblk = 192 blocks (compute per block ~2us; fine).
// ---------------------------------------------------------------------------
__global__ __launch_bounds__(256) void gemm3_mfma_kernel(
    const u16* __restrict__ Ahi, const u16* __restrict__ Alo,
    const u16* __restrict__ Bhi, const u16* __restrict__ Blo,
    float* __restrict__ ws_mx)
{
    const int tid = threadIdx.x;
    const int rt = blockIdx.x >> 3;            // 0..23 (row tile over 1536)
    const int ct = blockIdx.x & 7;             // 0..7  (col tile over 512)
    const int rloc  = (rt & 7) * 64;           // row base within X [0,512)
    const int brow0 = (rt >> 3) * 512 + ct * 64;   // row base within stacked W

    __shared__ __align__(16) u16 sAh[64 * 32];
    __shared__ __align__(16) u16 sAl[64 * 32];
    __shared__ __align__(16) u16 sBh[64 * 32];
    __shared__ __align__(16) u16 sBl[64 * 32];

    // staging: thread -> (row r, 16B k-slice s)
    const int r = tid >> 2, s = tid & 3;
    const u16* gAh = Ahi + (size_t)(rloc + r) * HID_ + s * 8;
    const u16* gAl = Alo + (size_t)(rloc + r) * HID_ + s * 8;
    const u16* gBh = Bhi + (size_t)(brow0 + r) * HID_ + s * 8;
    const u16* gBl = Blo + (size_t)(brow0 + r) * HID_ + s * 8;
    const int wslot = r * 32 + ((s ^ ((r >> 1) & 3)) * 8);

    // compute: wave (wr,wc) owns rows wr*32+[0,32), cols wc*32+[0,32)
    const int lane = tid & 63, w = tid >> 6;
    const int wr = w >> 1, wc = w & 1;
    const int fr = lane & 15;      // row/col within 16-frag
    const int fs = lane >> 4;      // k-slice 0..3
    int aslot[2], bslot[2];
    #pragma unroll
    for (int i = 0; i < 2; ++i) {
        const int ar = wr * 32 + i * 16 + fr;
        aslot[i] = ar * 32 + ((fs ^ ((ar >> 1) & 3)) * 8);
        const int br = wc * 32 + i * 16 + fr;
        bslot[i] = br * 32 + ((fs ^ ((br >> 1) & 3)) * 8);
    }

    f32x4 acc[2][2];
    #pragma unroll
    for (int i = 0; i < 2; ++i)
        #pragma unroll
        for (int j = 0; j < 2; ++j) acc[i][j] = (f32x4){0.f, 0.f, 0.f, 0.f};

    s16x8 pf0 = *(const s16x8*)gAh;
    s16x8 pf1 = *(const s16x8*)gAl;
    s16x8 pf2 = *(const s16x8*)gBh;
    s16x8 pf3 = *(const s16x8*)gBl;

    for (int k0 = 0; k0 < HID_; k0 += 32) {
        __syncthreads();                       // previous step's frag reads done
        *(s16x8*)&sAh[wslot] = pf0;
        *(s16x8*)&sAl[wslot] = pf1;
        *(s16x8*)&sBh[wslot] = pf2;
        *(s16x8*)&sBl[wslot] = pf3;
        __syncthreads();
        if (k0 + 32 < HID_) {                  // prefetch next k-chunk
            pf0 = *(const s16x8*)(gAh + k0 + 32);
            pf1 = *(const s16x8*)(gAl + k0 + 32);
            pf2 = *(const s16x8*)(gBh + k0 + 32);
            pf3 = *(const s16x8*)(gBl + k0 + 32);
        }
        s16x8 ah[2], al[2], bh[2], bl[2];
        #pragma unroll
        for (int i = 0; i < 2; ++i) {
            ah[i] = *(const s16x8*)&sAh[aslot[i]];
            al[i] = *(const s16x8*)&sAl[aslot[i]];
            bh[i] = *(const s16x8*)&sBh[bslot[i]];
            bl[i] = *(const s16x8*)&sBl[bslot[i]];
        }
        #pragma unroll
        for (int i = 0; i < 2; ++i)
            #pragma unroll
            for (int j = 0; j < 2; ++j) {
                acc[i][j] = __builtin_amdgcn_mfma_f32_16x16x32_bf16(ah[i], bh[j], acc[i][j], 0, 0, 0);
                acc[i][j] = __builtin_amdgcn_mfma_f32_16x16x32_bf16(ah[i], bl[j], acc[i][j], 0, 0, 0);
                acc[i][j] = __builtin_amdgcn_mfma_f32_16x16x32_bf16(al[i], bh[j], acc[i][j], 0, 0, 0);
            }
    }
    // epilogue: C/D col=lane&15, row=(lane>>4)*4+q
    #pragma unroll
    for (int i = 0; i < 2; ++i)
        #pragma unroll
        for (int j = 0; j < 2; ++j)
            #pragma unroll
            for (int q = 0; q < 4; ++q) {
                const int row = rt * 64 + wr * 32 + i * 16 + fs * 4 + q;
                const int col = ct * 64 + wc * 32 + j * 16 + fr;
                ws_mx[(size_t)row * HID_ + col] = acc[i][j][q];
            }
}

// ---------------------------------------------------------------------------
// Stage 1b: per-row mobius epilogue, ONE WAVE PER ROW (no barriers).
// In-place: reads mx row from ws_qkv, writes q/k/v (logmap0+chunk expmap0).
// gamma stored in FLAT CHUNK ORDER: ws_gamma[(b*S+s)*NH + j] — identical to
// [b][h][n] flat indexing through the reshape identity (chunk c=s*8+j=h*256+n).
// ---------------------------------------------------------------------------
__global__ __launch_bounds__(256) void mobius_rows_kernel(
    const float* __restrict__ query,
    const float* __restrict__ bq, const float* __restrict__ bk,
    const float* __restrict__ bv,
    float* __restrict__ ws_qkv, float* __restrict__ ws_gamma)
{
    const int lane = threadIdx.x & 63;
    const int wv   = threadIdx.x >> 6;
    const int row  = blockIdx.x * 4 + wv;     // 0..1535
    const int which = row >> 9;
    const int rr    = row & 511;              // b*S + s
    const float* __restrict__ bias = (which == 0) ? bq : (which == 1) ? bk : bv;
    float* mrow = ws_qkv + (size_t)row * HID_;
    const float* xrow = query + (size_t)((rr & 255) * 2 + (rr >> 8)) * HID_;

    float m[8], x[8], bb[8];
    *(float4*)&m[0]  = ((const float4*)mrow)[lane * 2];
    *(float4*)&m[4]  = ((const float4*)mrow)[lane * 2 + 1];
    *(float4*)&x[0]  = ((const float4*)xrow)[lane * 2];
    *(float4*)&x[4]  = ((const float4*)xrow)[lane * 2 + 1];
    *(float4*)&bb[0] = ((const float4*)bias)[lane * 2];
    *(float4*)&bb[4] = ((const float4*)bias)[lane * 2 + 1];

    float x2p = 0.f, m2p = 0.f, b2p = 0.f;
    #pragma unroll
    for (int j = 0; j < 8; ++j) {
        x2p = fmaf(x[j], x[j], x2p);
        m2p = fmaf(m[j], m[j], m2p);
        b2p = fmaf(bb[j], bb[j], b2p);
    }
    const float x2s = wsum64(x2p);
    const float mn2 = wsum64(m2p);
    const float b2s = wsum64(b2p);
    const float xn = fmaxf(sqrtf(x2s), 1e-15f);
    const float mn = fmaxf(sqrtf(mn2), 1e-15f);
    // mobius_matvec: res = tanh(mn/xn * artanh(xn)) * mx/mn
    const float fac = tanhf(mn / xn * artanh_c(xn)) / mn;
    float r[8];
    float r2p = 0.f, ryp = 0.f;
    #pragma unroll
    for (int j = 0; j < 8; ++j) {
        r[j] = fac * m[j];
        r2p = fmaf(r[j], r[j], r2p);
        ryp = fmaf(r[j], bb[j], ryp);
    }
    const float r2s = wsum64(r2p);
    const float ry  = wsum64(ryp);
    // mobius_add(r, bias)
    const float a_c = 1.f + 2.f * ry + b2s;
    const float b_c = 1.f - r2s;
    const float den = 1.f + 2.f * ry + r2s * b2s;
    const float inv_den = 1.f / fmaxf(den, 1e-15f);
    float h[8];
    float h2p = 0.f;
    #pragma unroll
    for (int j = 0; j < 8; ++j) {
        h[j] = (a_c * r[j] + b_c * bb[j]) * inv_den;
        h2p = fmaf(h[j], h[j], h2p);
    }
    const float h2s = wsum64(h2p);
    float hn = fmaxf(sqrtf(h2s), 1e-15f);
    float pf = 1.f;
    if (hn > 0.996f) { pf = 0.996f / hn; hn = 0.996f; }   // projx
    const float lf = artanh_c(hn) / hn * pf;               // logmap0 (512-dim)
    float l[8];
    float l2p = 0.f;
    #pragma unroll
    for (int j = 0; j < 8; ++j) {
        l[j] = lf * h[j];
        l2p = fmaf(l[j], l[j], l2p);
    }
    // expmap0 over flat 64-chunks: chunk j = lanes j*8 .. j*8+7
    float cs = l2p;
    cs += __shfl_xor(cs, 1, 64);
    cs += __shfl_xor(cs, 2, 64);
    cs += __shfl_xor(cs, 4, 64);
    const float cn = fmaxf(sqrtf(cs), 1e-15f);
    const float th = tanhf(cn);
    const float sc = th / cn;
    float o[8];
    #pragma unroll
    for (int j = 0; j < 8; ++j) o[j] = sc * l[j];
    ((float4*)mrow)[lane * 2]     = *(float4*)&o[0];
    ((float4*)mrow)[lane * 2 + 1] = *(float4*)&o[4];
    if (which == 2 && (lane & 7) == 0) {
        const int j = lane >> 3;
        // gamma = 2 / max(1 - ||vl_chunk||^2, eps); ||vl_chunk|| = tanh(cn)
        ws_gamma[(size_t)rr * NH_ + j] = 2.f / fmaxf(1.f - th * th, 1e-15f);
    }
}

// ---------------------------------------------------------------------------
// Stage 2+3 FUSED: scores/probs + weighted gyro-midpoint + scalar_mul + logmap0.
// Block = (bh, 8-q tile), 512 blocks x 256 threads.
// Phase A: K staged in two 128-row LDS halves (XOR-swizzled); per-row |k|^2
//   precomputed during staging (k2 is q-independent — was computed 8x).
//   u-loop factored: u = a_c*(r_c*k - q), r_c = b_c/a_c (a_c>0 strictly since
//   |q|,|k|<1: a_c = (1-|k|)^2 + 2|k|(1-|q|·cos) > 0), so
//   sum 1/(u^2+c2) = (1/a_c^2) * sum 1/(w^2 + c2/a_c^2): 3 VALU + rcp per d.
// Phase B: wave w owns n in [64w,64w+64) for ALL 8 q (vl read once per block,
//   not 4x), partials combined via LDS.
// NOTE: lc must NOT alias ql (other blocks still read ql in phase A).
// ---------------------------------------------------------------------------
__global__ __launch_bounds__(256) void attn_kernel(
    const float* __restrict__ ws_qkv, const float* __restrict__ gamma,
    float* __restrict__ probs, float* __restrict__ lc)
{
    const int tid = threadIdx.x;
    const int bh  = blockIdx.x >> 5;
    const int q0  = (blockIdx.x & 31) * 8;
    const float* __restrict__ ql = ws_qkv + (size_t)bh * (S_ * HD_);
    const float* __restrict__ kl = ws_qkv + (size_t)BSH + (size_t)bh * (S_ * HD_);
    const float* __restrict__ vl = ws_qkv + (size_t)2 * BSH + (size_t)bh * (S_ * HD_);

    __shared__ __align__(16) float kS[128 * 64];   // 32 KB, swizzled
    __shared__ __align__(16) float qS[8 * 64];     // 2 KB
    __shared__ __align__(16) float pS[8 * 256];    // 8 KB: p*gamma, [q_local][n]
    __shared__ float gS[S_];                       // 1 KB
    __shared__ float k2S[128];                     // per-row |k|^2, per half
    __shared__ float nomP[4][8][64];               // 8 KB phase-B partials
    __shared__ float dnS[8];

    // gamma in flat-chunk order == [b][h][n] flat => contiguous at bh*S_
    gS[tid] = gamma[(size_t)bh * S_ + tid];
    if (tid < 128) ((float4*)qS)[tid] = ((const float4*)(ql + (size_t)q0 * 64))[tid];
    __syncthreads();

    const int q_l = tid >> 5;       // 0..7
    const int n_i = tid & 31;       // 0..31
    float qv[64];
    #pragma unroll
    for (int c = 0; c < 16; ++c)
        *(float4*)&qv[c * 4] = *(const float4*)&qS[q_l * 64 + c * 4];
    float q2 = 0.f;
    #pragma unroll
    for (int d = 0; d < 64; ++d) q2 = fmaf(qv[d], qv[d], q2);
    const float b_c = 1.f - q2;
    float* __restrict__ prow = probs + ((size_t)(bh * S_ + q0 + q_l)) * S_;

    const int c4 = tid & 15;        // staging: chunk
    const int nb = tid >> 4;        // staging: row base
    float sp = 0.f, spg = 0.f;

    for (int half = 0; half < 2; ++half) {
        __syncthreads();            // protect kS/k2S reuse across halves
        #pragma unroll
        for (int jj = 0; jj < 8; ++jj) {
            const int n = nb + 16 * jj;   // 0..127
            const float4 v = *(const float4*)(kl + ((size_t)(half * 128 + n)) * 64 + c4 * 4);
            *(float4*)&kS[n * 64 + ((c4 ^ (n & 15)) * 4)] = v;
            // per-row |k|^2: reduce 16 chunk-partials over the 16 lanes sharing nb
            float pk = fmaf(v.x, v.x, fmaf(v.y, v.y, fmaf(v.z, v.z, v.w * v.w)));
            pk += __shfl_xor(pk, 1, 64);
            pk += __shfl_xor(pk, 2, 64);
            pk += __shfl_xor(pk, 4, 64);
            pk += __shfl_xor(pk, 8, 64);
            if (c4 == 0) k2S[n] = pk;
        }
        __syncthreads();
        #pragma unroll
        for (int j = 0; j < 4; ++j) {
            const int n = n_i + 32 * j;   // within half
            float kv[64];
            #pragma unroll
            for (int c = 0; c < 16; ++c)
                *(float4*)&kv[c * 4] = *(const float4*)&kS[n * 64 + ((c ^ (n & 15)) * 4)];
            float s = 0.f;
            #pragma unroll
            for (int d = 0; d < 64; ++d) s = fmaf(qv[d], kv[d], s);
            const float k2  = k2S[n];
            const float a_c = 1.f - 2.f * s + k2;
            const float den = fmaxf(fmaf(q2, k2, 1.f - 2.f * s), 1e-15f);
            const float ra  = __builtin_amdgcn_rcpf(a_c);
            const float r_c = b_c * ra;
            const float scale = den * den * ra * ra;   // den^2 / a_c^2
            const float c2  = 1e-30f * scale;
            float invsum = 0.f;
            #pragma unroll
            for (int d = 0; d < 64; ++d) {
                const float w = fmaf(r_c, kv[d], -qv[d]);
                invsum += __builtin_amdgcn_rcpf(fmaf(w, w, c2));
            }
            const float t1 = __builtin_amdgcn_rsqf(scale * invsum);
            const float p = 0.5f - 0.5f * fminf(t1, 0.9999999f);
            const int gn = half * 128 + n;
            prow[gn] = p;
            const float g = gS[gn];
            pS[q_l * 256 + gn] = p * g;
            sp += p; spg += p * g;
        }
    }
    // reduce sp/spg over the 32 threads sharing q_l (lanes [0,32) / [32,64))
    #pragma unroll
    for (int o = 1; o < 32; o <<= 1) {
        sp  += __shfl_xor(sp, o, 64);
        spg += __shfl_xor(spg, o, 64);
    }
    if ((tid & 31) == 0) dnS[q_l] = spg - sp;   // denom = sum p*(g-1)
    __syncthreads();

    // Phase B: wave w owns n in [64w, 64w+64), all 8 q; lane = d
    const int w = tid >> 6, d = tid & 63;
    float acc[8] = {};
    const float* __restrict__ vbase = vl + (size_t)(w * 64) * 64;
    #pragma unroll 4
    for (int i4 = 0; i4 < 16; ++i4) {
        float vv[4];
        #pragma unroll
        for (int j2 = 0; j2 < 4; ++j2) vv[j2] = vbase[(size_t)(i4 * 4 + j2) * 64 + d];
        #pragma unroll
        for (int qq = 0; qq < 8; ++qq) {
            const float4 pq = *(const float4*)&pS[qq * 256 + w * 64 + i4 * 4]; // broadcast
            acc[qq] = fmaf(pq.x, vv[0], acc[qq]);
            acc[qq] = fmaf(pq.y, vv[1], acc[qq]);
            acc[qq] = fmaf(pq.z, vv[2], acc[qq]);
            acc[qq] = fmaf(pq.w, vv[3], acc[qq]);
        }
    }
    #pragma unroll
    for (int qq = 0; qq < 8; ++qq) nomP[w][qq][d] = acc[qq];
    __syncthreads();

    #pragma unroll
    for (int t = 0; t < 2; ++t) {
        const int qq = (tid >> 6) + 4 * t;
        const float nom = nomP[0][qq][d] + nomP[1][qq][d] + nomP[2][qq][d] + nomP[3][qq][d];
        const float dd = dnS[qq];
        const float adn = fmaxf(fabsf(dd), 1e-10f);
        const float sden = (dd >= 0.f) ? adn : -adn;
        const float m = nom / sden;
        const float ss = wsum64(m * m);
        const float nn = fmaxf(sqrtf(ss), 1e-15f);
        const float s1 = tanhf(0.5f * artanh_c(nn));     // mobius_scalar_mul(0.5)
        const float res = s1 * m / nn;
        const float nres = fmaxf(s1, 1e-15f);            // ||res|| = s1 >= 0
        lc[((size_t)(bh * S_ + q0 + qq)) * HD_ + d] = (artanh_c(nres) / nres) * res;
    }
}

// ---------------------------------------------------------------------------
// Stage 4: gather heads -> [B,Q,512] row, expmap0 over 512, store [S,B,HID].
// ---------------------------------------------------------------------------
__global__ __launch_bounds__(256) void outproj_kernel(
    const float* __restrict__ lc, float* __restrict__ out0)
{
    const int t = threadIdx.x;
    const int s = blockIdx.x & (S_ - 1);
    const int b = blockIdx.x >> 8;
    __shared__ float red[256];
    const int h0 = t >> 6, d0 = t & 63;
    const int e1 = t + 256;
    const int h1 = e1 >> 6, d1 = e1 & 63;
    const float v0 = lc[(((size_t)(b * NH_ + h0)) * S_ + s) * HD_ + d0];
    const float v1 = lc[(((size_t)(b * NH_ + h1)) * S_ + s) * HD_ + d1];
    const float ss = block_sum_256(v0 * v0 + v1 * v1, red);
    const float nn = fmaxf(sqrtf(ss), 1e-15f);
    const float f = tanhf(nn) / nn;
    float* orow = out0 + ((size_t)(s * B_ + b)) * HID_;
    orow[t] = f * v0;
    orow[t + 256] = f * v1;
}

extern "C" void kernel_launch(void* const* d_in, const int* in_sizes, int n_in,
                              void* d_out, int out_size, void* d_ws, size_t ws_size,
                              hipStream_t stream) {
    (void)in_sizes; (void)n_in; (void)out_size; (void)ws_size;
    const float* query = (const float*)d_in[0];
    const float* Wq = (const float*)d_in[1];
    const float* bq = (const float*)d_in[2];
    const float* Wk = (const float*)d_in[3];
    const float* bk = (const float*)d_in[4];
    const float* Wv = (const float*)d_in[5];
    const float* bv = (const float*)d_in[6];

    float* out0  = (float*)d_out;                          // [S,B,HID] = 262144
    float* probs = out0 + (size_t)S_ * B_ * HID_;          // [B,NH,S,S] = 1048576

    float* ws       = (float*)d_ws;
    float* ws_qkv   = ws;                                  // mx -> ql|kl|vl : 3*262144 floats
    float* ws_gamma = ws + (size_t)3 * BSH;                // 4096 floats, flat chunk order
    float* ws_lc    = ws + (size_t)3 * BSH + 4096;         // 131072 floats (NO alias: attn
                                                           // writes lc while other blocks read ql)
    // bf16 hi/lo operand area (4 MB), 16B-aligned boundary
    u16* Ahi = (u16*)(ws + (size_t)3 * BSH + 4096 + 131072);
    u16* Alo = Ahi + (size_t)512 * HID_;                   // 512x512 each
    u16* Bhi = Alo + (size_t)512 * HID_;                   // 1536x512 each
    u16* Blo = Bhi + (size_t)1536 * HID_;

    cvt_kernel<<<dim3(512), dim3(256), 0, stream>>>(query, Wq, Wk, Wv, Ahi, Alo, Bhi, Blo);
    gemm3_mfma_kernel<<<dim3(192), dim3(256), 0, stream>>>(Ahi, Alo, Bhi, Blo, ws_qkv);
    mobius_rows_kernel<<<dim3(384), dim3(256), 0, stream>>>(query, bq, bk, bv, ws_qkv, ws_gamma);
    attn_kernel<<<dim3(512), dim3(256), 0, stream>>>(ws_qkv, ws_gamma, probs, ws_lc);
    outproj_kernel<<<dim3(B_ * S_), dim3(256), 0, stream>>>(ws_lc, out0);
}

// Round 4
// 108.849 us; speedup vs baseline: 1.6193x; 1.0171x over previous
//
#include <hip/hip_runtime.h>
#include <math.h>

// Problem constants (reference: S=256, B=2, HID=512, NH=8, HD=64, C=1)
constexpr int S_   = 256;
constexpr int B_   = 2;
constexpr int HID_ = 512;
constexpr int NH_  = 8;
constexpr int HD_  = 64;
constexpr int BSH  = B_ * S_ * HID_;   // 262144

typedef unsigned short u16;
typedef short s16x8 __attribute__((ext_vector_type(8)));
typedef float f32x4 __attribute__((ext_vector_type(4)));

__device__ __forceinline__ float artanh_c(float x) {
    // reference _artanh: clip to [-1+1e-7, 1-1e-7], then artanh
    x = fminf(fmaxf(x, -0.9999999f), 0.9999999f);
    return 0.5f * __logf((1.f + x) / (1.f - x));
}

__device__ __forceinline__ float wsum64(float v) {
    #pragma unroll
    for (int o = 1; o < 64; o <<= 1) v += __shfl_xor(v, o, 64);
    return v;
}

__device__ __forceinline__ float block_sum_256(float v, float* red) {
    const int t = threadIdx.x;
    __syncthreads();              // protect previous use of red
    red[t] = v;
    __syncthreads();
    #pragma unroll
    for (int sft = 128; sft > 0; sft >>= 1) {
        if (t < sft) red[t] += red[t + sft];
        __syncthreads();
    }
    return red[0];
}

// fp32 -> bf16 hi/lo split (exact residual: a = hi + lo + O(2^-16 a))
__device__ __forceinline__ void split8(const float* v, s16x8& hi, s16x8& lo) {
    #pragma unroll
    for (int j = 0; j < 8; ++j) {
        const unsigned u = __float_as_uint(v[j]);
        const float hf = __uint_as_float(u & 0xFFFF0000u);
        hi[j] = (short)(u >> 16);
        lo[j] = (short)(__float_as_uint(v[j] - hf) >> 16);
    }
}

// ---------------------------------------------------------------------------
// Stage 1a: mx = x @ W^T via bf16 MFMA, hi/lo compensated:
//   C = Ahi*Bhi^T + Ahi*Blo^T + Alo*Bhi^T  (fp32 accum; dropped Alo*Blo term
//   ~2^-16 relative). v5 post-mortem of v4 (cvt+gemm = 31 us by delta):
//   * cvt FUSED into staging (fp32 global load -> in-reg hi/lo split -> bf16
//     LDS write). No bf16 round-trip through L2, one launch fewer.
//   * PING-PONG LDS, ONE barrier per K64-chunk; global loads issued AFTER the
//     barrier and consumed by the write BEFORE the next barrier, so the
//     __syncthreads vmcnt(0) drain costs nothing (v4 issued loads right
//     before the barrier -> full latency exposed on all 16 steps).
//   * 32x64 tiles -> 384 blocks (1.5/CU, was 0.75/CU).
// Block: 4 waves, wave tile 32x16: per K64-chunk per wave 12 ds_read_b128 +
// 12 MFMA (16x16x32). LDS 48 KB. Frag layouts as v4 (validated by absmax):
//   A row=lane&15, k=(lane>>4)*8+j; B col=lane&15; C/D col=lane&15,
//   row=(lane>>4)*4+reg. Swizzle: slot = (slice ^ (row&7)) on both sides.
// ---------------------------------------------------------------------------
__global__ __launch_bounds__(256) void gemm3_fused_kernel(
    const float* __restrict__ query,
    const float* __restrict__ Wq, const float* __restrict__ Wk,
    const float* __restrict__ Wv, float* __restrict__ ws_mx)
{
    const int tid = threadIdx.x;
    const int rt = blockIdx.x >> 3;            // 0..47 (32-row tiles over 1536)
    const int ct = blockIdx.x & 7;             // 0..7  (64-col tiles)
    const int which = (rt * 32) >> 9;
    const int rloc  = (rt * 32) & 511;
    const float* __restrict__ W = (which == 0) ? Wq : (which == 1) ? Wk : Wv;

    __shared__ __align__(16) u16 sA[2][2][32 * 64];   // [buf][hi/lo] 16 KB
    __shared__ __align__(16) u16 sB[2][2][64 * 64];   // [buf][hi/lo] 32 KB

    // staging: A thread -> (row ra, slice sa); B thread -> (row rb, slices hb,hb+1)
    const int ra = tid >> 3, sa = tid & 7;
    const int rb = tid >> 2, hb = (tid & 3) * 2;
    const int axrow = rloc + ra;
    const float* gA = query + (size_t)((axrow & 255) * 2 + (axrow >> 8)) * HID_ + sa * 8;
    const float* gB = W + (size_t)(ct * 64 + rb) * HID_ + hb * 8;
    const int wA  = ra * 64 + ((sa ^ (ra & 7)) * 8);
    const int wB0 = rb * 64 + ((hb ^ (rb & 7)) * 8);
    const int wB1 = rb * 64 + (((hb + 1) ^ (rb & 7)) * 8);

    // compute: wave wv owns cols wv*16+[0,16), all 32 rows (2 A-frags)
    const int lane = tid & 63, wv = tid >> 6;
    const int fr = lane & 15, fs = lane >> 4;
    const int aB0 = fr * 64,        ax0 = fr & 7;
    const int aB1 = (16 + fr) * 64, ax1 = (16 + fr) & 7;
    const int bB  = (wv * 16 + fr) * 64, bx = (wv * 16 + fr) & 7;

    float a8[8], b16[16];
    f32x4 acc[2] = {(f32x4){0.f,0.f,0.f,0.f}, (f32x4){0.f,0.f,0.f,0.f}};

#define G3_LOAD(c)  do { \
        const int k0 = (c) * 64; \
        *(float4*)&a8[0]  = *(const float4*)(gA + k0); \
        *(float4*)&a8[4]  = *(const float4*)(gA + k0 + 4); \
        *(float4*)&b16[0] = *(const float4*)(gB + k0); \
        *(float4*)&b16[4] = *(const float4*)(gB + k0 + 4); \
        *(float4*)&b16[8] = *(const float4*)(gB + k0 + 8); \
        *(float4*)&b16[12]= *(const float4*)(gB + k0 + 12); \
    } while (0)

#define G3_WRITE(b) do { \
        s16x8 h_, l_; \
        split8(a8, h_, l_); \
        *(s16x8*)&sA[b][0][wA] = h_;  *(s16x8*)&sA[b][1][wA] = l_; \
        split8(&b16[0], h_, l_); \
        *(s16x8*)&sB[b][0][wB0] = h_; *(s16x8*)&sB[b][1][wB0] = l_; \
        split8(&b16[8], h_, l_); \
        *(s16x8*)&sB[b][0][wB1] = h_; *(s16x8*)&sB[b][1][wB1] = l_; \
    } while (0)

    G3_LOAD(0);
    G3_WRITE(0);

    for (int c = 0; c < 8; ++c) {
        const int p = c & 1;
        __syncthreads();                     // buf p written & prior reads done
        if (c < 7) G3_LOAD(c + 1);           // issued after barrier: latency
                                             // covered by compute below
        #pragma unroll
        for (int h = 0; h < 2; ++h) {
            const int sl = h * 4 + fs;
            s16x8 ah0 = *(const s16x8*)&sA[p][0][aB0 + ((sl ^ ax0) * 8)];
            s16x8 al0 = *(const s16x8*)&sA[p][1][aB0 + ((sl ^ ax0) * 8)];
            s16x8 ah1 = *(const s16x8*)&sA[p][0][aB1 + ((sl ^ ax1) * 8)];
            s16x8 al1 = *(const s16x8*)&sA[p][1][aB1 + ((sl ^ ax1) * 8)];
            s16x8 bh  = *(const s16x8*)&sB[p][0][bB  + ((sl ^ bx)  * 8)];
            s16x8 bl  = *(const s16x8*)&sB[p][1][bB  + ((sl ^ bx)  * 8)];
            acc[0] = __builtin_amdgcn_mfma_f32_16x16x32_bf16(ah0, bh, acc[0], 0, 0, 0);
            acc[0] = __builtin_amdgcn_mfma_f32_16x16x32_bf16(ah0, bl, acc[0], 0, 0, 0);
            acc[0] = __builtin_amdgcn_mfma_f32_16x16x32_bf16(al0, bh, acc[0], 0, 0, 0);
            acc[1] = __builtin_amdgcn_mfma_f32_16x16x32_bf16(ah1, bh, acc[1], 0, 0, 0);
            acc[1] = __builtin_amdgcn_mfma_f32_16x16x32_bf16(ah1, bl, acc[1], 0, 0, 0);
            acc[1] = __builtin_amdgcn_mfma_f32_16x16x32_bf16(al1, bh, acc[1], 0, 0, 0);
        }
        if (c < 7) G3_WRITE((c + 1) & 1);    // other buffer: no WAR with current
                                             // readers; visible after next barrier
    }
#undef G3_LOAD
#undef G3_WRITE

    // epilogue: C/D col=fr, row=fs*4+q within each 16x16 frag
    #pragma unroll
    for (int i = 0; i < 2; ++i)
        #pragma unroll
        for (int q = 0; q < 4; ++q)
            ws_mx[(size_t)(rt * 32 + i * 16 + fs * 4 + q) * HID_ + ct * 64 + wv * 16 + fr]
                = acc[i][q];
}

// ---------------------------------------------------------------------------
// Stage 1b: per-row mobius epilogue, ONE WAVE PER ROW (no barriers).
// In-place: reads mx row from ws_qkv, writes q/k/v (logmap0+chunk expmap0).
// gamma stored in FLAT CHUNK ORDER: ws_gamma[(b*S+s)*NH + j] — identical to
// [b][h][n] flat indexing through the reshape identity (chunk c=s*8+j=h*256+n).
// ---------------------------------------------------------------------------
__global__ __launch_bounds__(256) void mobius_rows_kernel(
    const float* __restrict__ query,
    const float* __restrict__ bq, const float* __restrict__ bk,
    const float* __restrict__ bv,
    float* __restrict__ ws_qkv, float* __restrict__ ws_gamma)
{
    const int lane = threadIdx.x & 63;
    const int wv   = threadIdx.x >> 6;
    const int row  = blockIdx.x * 4 + wv;     // 0..1535
    const int which = row >> 9;
    const int rr    = row & 511;              // b*S + s
    const float* __restrict__ bias = (which == 0) ? bq : (which == 1) ? bk : bv;
    float* mrow = ws_qkv + (size_t)row * HID_;
    const float* xrow = query + (size_t)((rr & 255) * 2 + (rr >> 8)) * HID_;

    float m[8], x[8], bb[8];
    *(float4*)&m[0]  = ((const float4*)mrow)[lane * 2];
    *(float4*)&m[4]  = ((const float4*)mrow)[lane * 2 + 1];
    *(float4*)&x[0]  = ((const float4*)xrow)[lane * 2];
    *(float4*)&x[4]  = ((const float4*)xrow)[lane * 2 + 1];
    *(float4*)&bb[0] = ((const float4*)bias)[lane * 2];
    *(float4*)&bb[4] = ((const float4*)bias)[lane * 2 + 1];

    float x2p = 0.f, m2p = 0.f, b2p = 0.f;
    #pragma unroll
    for (int j = 0; j < 8; ++j) {
        x2p = fmaf(x[j], x[j], x2p);
        m2p = fmaf(m[j], m[j], m2p);
        b2p = fmaf(bb[j], bb[j], b2p);
    }
    const float x2s = wsum64(x2p);
    const float mn2 = wsum64(m2p);
    const float b2s = wsum64(b2p);
    const float xn = fmaxf(sqrtf(x2s), 1e-15f);
    const float mn = fmaxf(sqrtf(mn2), 1e-15f);
    // mobius_matvec: res = tanh(mn/xn * artanh(xn)) * mx/mn
    const float fac = tanhf(mn / xn * artanh_c(xn)) / mn;
    float r[8];
    float r2p = 0.f, ryp = 0.f;
    #pragma unroll
    for (int j = 0; j < 8; ++j) {
        r[j] = fac * m[j];
        r2p = fmaf(r[j], r[j], r2p);
        ryp = fmaf(r[j], bb[j], ryp);
    }
    const float r2s = wsum64(r2p);
    const float ry  = wsum64(ryp);
    // mobius_add(r, bias)
    const float a_c = 1.f + 2.f * ry + b2s;
    const float b_c = 1.f - r2s;
    const float den = 1.f + 2.f * ry + r2s * b2s;
    const float inv_den = 1.f / fmaxf(den, 1e-15f);
    float h[8];
    float h2p = 0.f;
    #pragma unroll
    for (int j = 0; j < 8; ++j) {
        h[j] = (a_c * r[j] + b_c * bb[j]) * inv_den;
        h2p = fmaf(h[j], h[j], h2p);
    }
    const float h2s = wsum64(h2p);
    float hn = fmaxf(sqrtf(h2s), 1e-15f);
    float pf = 1.f;
    if (hn > 0.996f) { pf = 0.996f / hn; hn = 0.996f; }   // projx
    const float lf = artanh_c(hn) / hn * pf;               // logmap0 (512-dim)
    float l[8];
    float l2p = 0.f;
    #pragma unroll
    for (int j = 0; j < 8; ++j) {
        l[j] = lf * h[j];
        l2p = fmaf(l[j], l[j], l2p);
    }
    // expmap0 over flat 64-chunks: chunk j = lanes j*8 .. j*8+7
    float cs = l2p;
    cs += __shfl_xor(cs, 1, 64);
    cs += __shfl_xor(cs, 2, 64);
    cs += __shfl_xor(cs, 4, 64);
    const float cn = fmaxf(sqrtf(cs), 1e-15f);
    const float th = tanhf(cn);
    const float sc = th / cn;
    float o[8];
    #pragma unroll
    for (int j = 0; j < 8; ++j) o[j] = sc * l[j];
    ((float4*)mrow)[lane * 2]     = *(float4*)&o[0];
    ((float4*)mrow)[lane * 2 + 1] = *(float4*)&o[4];
    if (which == 2 && (lane & 7) == 0) {
        const int j = lane >> 3;
        // gamma = 2 / max(1 - ||vl_chunk||^2, eps); ||vl_chunk|| = tanh(cn)
        ws_gamma[(size_t)rr * NH_ + j] = 2.f / fmaxf(1.f - th * th, 1e-15f);
    }
}

// ---------------------------------------------------------------------------
// Stage 2+3 FUSED: scores/probs + weighted gyro-midpoint + scalar_mul + logmap0.
// Block = (bh, 8-q tile), 512 blocks x 256 threads.
// Phase A: K staged in two 128-row LDS halves (XOR-swizzled); per-row |k|^2
//   precomputed during staging (k2 is q-independent — was computed 8x).
//   u-loop factored: u = a_c*(r_c*k - q), r_c = b_c/a_c (a_c>0 strictly since
//   |q|,|k|<1: a_c = (1-|k|)^2 + 2|k|(1-|q|·cos) > 0), so
//   sum 1/(u^2+c2) = (1/a_c^2) * sum 1/(w^2 + c2/a_c^2): 3 VALU + rcp per d.
// Phase B: wave w owns n in [64w,64w+64) for ALL 8 q (vl read once per block,
//   not 4x), partials combined via LDS.
// NOTE: lc must NOT alias ql (other blocks still read ql in phase A).
// ---------------------------------------------------------------------------
__global__ __launch_bounds__(256) void attn_kernel(
    const float* __restrict__ ws_qkv, const float* __restrict__ gamma,
    float* __restrict__ probs, float* __restrict__ lc)
{
    const int tid = threadIdx.x;
    const int bh  = blockIdx.x >> 5;
    const int q0  = (blockIdx.x & 31) * 8;
    const float* __restrict__ ql = ws_qkv + (size_t)bh * (S_ * HD_);
    const float* __restrict__ kl = ws_qkv + (size_t)BSH + (size_t)bh * (S_ * HD_);
    const float* __restrict__ vl = ws_qkv + (size_t)2 * BSH + (size_t)bh * (S_ * HD_);

    __shared__ __align__(16) float kS[128 * 64];   // 32 KB, swizzled
    __shared__ __align__(16) float qS[8 * 64];     // 2 KB
    __shared__ __align__(16) float pS[8 * 256];    // 8 KB: p*gamma, [q_local][n]
    __shared__ float gS[S_];                       // 1 KB
    __shared__ float k2S[128];                     // per-row |k|^2, per half
    __shared__ float nomP[4][8][64];               // 8 KB phase-B partials
    __shared__ float dnS[8];

    // gamma in flat-chunk order == [b][h][n] flat => contiguous at bh*S_
    gS[tid] = gamma[(size_t)bh * S_ + tid];
    if (tid < 128) ((float4*)qS)[tid] = ((const float4*)(ql + (size_t)q0 * 64))[tid];
    __syncthreads();

    const int q_l = tid >> 5;       // 0..7
    const int n_i = tid & 31;       // 0..31
    float qv[64];
    #pragma unroll
    for (int c = 0; c < 16; ++c)
        *(float4*)&qv[c * 4] = *(const float4*)&qS[q_l * 64 + c * 4];
    float q2 = 0.f;
    #pragma unroll
    for (int d = 0; d < 64; ++d) q2 = fmaf(qv[d], qv[d], q2);
    const float b_c = 1.f - q2;
    float* __restrict__ prow = probs + ((size_t)(bh * S_ + q0 + q_l)) * S_;

    const int c4 = tid & 15;        // staging: chunk
    const int nb = tid >> 4;        // staging: row base
    float sp = 0.f, spg = 0.f;

    for (int half = 0; half < 2; ++half) {
        __syncthreads();            // protect kS/k2S reuse across halves
        #pragma unroll
        for (int jj = 0; jj < 8; ++jj) {
            const int n = nb + 16 * jj;   // 0..127
            const float4 v = *(const float4*)(kl + ((size_t)(half * 128 + n)) * 64 + c4 * 4);
            *(float4*)&kS[n * 64 + ((c4 ^ (n & 15)) * 4)] = v;
            // per-row |k|^2: reduce 16 chunk-partials over the 16 lanes sharing nb
            float pk = fmaf(v.x, v.x, fmaf(v.y, v.y, fmaf(v.z, v.z, v.w * v.w)));
            pk += __shfl_xor(pk, 1, 64);
            pk += __shfl_xor(pk, 2, 64);
            pk += __shfl_xor(pk, 4, 64);
            pk += __shfl_xor(pk, 8, 64);
            if (c4 == 0) k2S[n] = pk;
        }
        __syncthreads();
        #pragma unroll
        for (int j = 0; j < 4; ++j) {
            const int n = n_i + 32 * j;   // within half
            float kv[64];
            #pragma unroll
            for (int c = 0; c < 16; ++c)
                *(float4*)&kv[c * 4] = *(const float4*)&kS[n * 64 + ((c ^ (n & 15)) * 4)];
            float s = 0.f;
            #pragma unroll
            for (int d = 0; d < 64; ++d) s = fmaf(qv[d], kv[d], s);
            const float k2  = k2S[n];
            const float a_c = 1.f - 2.f * s + k2;
            const float den = fmaxf(fmaf(q2, k2, 1.f - 2.f * s), 1e-15f);
            const float ra  = __builtin_amdgcn_rcpf(a_c);
            const float r_c = b_c * ra;
            const float scale = den * den * ra * ra;   // den^2 / a_c^2
            const float c2  = 1e-30f * scale;
            float invsum = 0.f;
            #pragma unroll
            for (int d = 0; d < 64; ++d) {
                const float w = fmaf(r_c, kv[d], -qv[d]);
                invsum += __builtin_amdgcn_rcpf(fmaf(w, w, c2));
            }
            const float t1 = __builtin_amdgcn_rsqf(scale * invsum);
            const float p = 0.5f - 0.5f * fminf(t1, 0.9999999f);
            const int gn = half * 128 + n;
            prow[gn] = p;
            const float g = gS[gn];
            pS[q_l * 256 + gn] = p * g;
            sp += p; spg += p * g;
        }
    }
    // reduce sp/spg over the 32 threads sharing q_l (lanes [0,32) / [32,64))
    #pragma unroll
    for (int o = 1; o < 32; o <<= 1) {
        sp  += __shfl_xor(sp, o, 64);
        spg += __shfl_xor(spg, o, 64);
    }
    if ((tid & 31) == 0) dnS[q_l] = spg - sp;   // denom = sum p*(g-1)
    __syncthreads();

    // Phase B: wave w owns n in [64w, 64w+64), all 8 q; lane = d
    const int w = tid >> 6, d = tid & 63;
    float acc[8] = {};
    const float* __restrict__ vbase = vl + (size_t)(w * 64) * 64;
    #pragma unroll 4
    for (int i4 = 0; i4 < 16; ++i4) {
        float vv[4];
        #pragma unroll
        for (int j2 = 0; j2 < 4; ++j2) vv[j2] = vbase[(size_t)(i4 * 4 + j2) * 64 + d];
        #pragma unroll
        for (int qq = 0; qq < 8; ++qq) {
            const float4 pq = *(const float4*)&pS[qq * 256 + w * 64 + i4 * 4]; // broadcast
            acc[qq] = fmaf(pq.x, vv[0], acc[qq]);
            acc[qq] = fmaf(pq.y, vv[1], acc[qq]);
            acc[qq] = fmaf(pq.z, vv[2], acc[qq]);
            acc[qq] = fmaf(pq.w, vv[3], acc[qq]);
        }
    }
    #pragma unroll
    for (int qq = 0; qq < 8; ++qq) nomP[w][qq][d] = acc[qq];
    __syncthreads();

    #pragma unroll
    for (int t = 0; t < 2; ++t) {
        const int qq = (tid >> 6) + 4 * t;
        const float nom = nomP[0][qq][d] + nomP[1][qq][d] + nomP[2][qq][d] + nomP[3][qq][d];
        const float dd = dnS[qq];
        const float adn = fmaxf(fabsf(dd), 1e-10f);
        const float sden = (dd >= 0.f) ? adn : -adn;
        const float m = nom / sden;
        const float ss = wsum64(m * m);
        const float nn = fmaxf(sqrtf(ss), 1e-15f);
        const float s1 = tanhf(0.5f * artanh_c(nn));     // mobius_scalar_mul(0.5)
        const float res = s1 * m / nn;
        const float nres = fmaxf(s1, 1e-15f);            // ||res|| = s1 >= 0
        lc[((size_t)(bh * S_ + q0 + qq)) * HD_ + d] = (artanh_c(nres) / nres) * res;
    }
}

// ---------------------------------------------------------------------------
// Stage 4: gather heads -> [B,Q,512] row, expmap0 over 512, store [S,B,HID].
// ---------------------------------------------------------------------------
__global__ __launch_bounds__(256) void outproj_kernel(
    const float* __restrict__ lc, float* __restrict__ out0)
{
    const int t = threadIdx.x;
    const int s = blockIdx.x & (S_ - 1);
    const int b = blockIdx.x >> 8;
    __shared__ float red[256];
    const int h0 = t >> 6, d0 = t & 63;
    const int e1 = t + 256;
    const int h1 = e1 >> 6, d1 = e1 & 63;
    const float v0 = lc[(((size_t)(b * NH_ + h0)) * S_ + s) * HD_ + d0];
    const float v1 = lc[(((size_t)(b * NH_ + h1)) * S_ + s) * HD_ + d1];
    const float ss = block_sum_256(v0 * v0 + v1 * v1, red);
    const float nn = fmaxf(sqrtf(ss), 1e-15f);
    const float f = tanhf(nn) / nn;
    float* orow = out0 + ((size_t)(s * B_ + b)) * HID_;
    orow[t] = f * v0;
    orow[t + 256] = f * v1;
}

extern "C" void kernel_launch(void* const* d_in, const int* in_sizes, int n_in,
                              void* d_out, int out_size, void* d_ws, size_t ws_size,
                              hipStream_t stream) {
    (void)in_sizes; (void)n_in; (void)out_size; (void)ws_size;
    const float* query = (const float*)d_in[0];
    const float* Wq = (const float*)d_in[1];
    const float* bq = (const float*)d_in[2];
    const float* Wk = (const float*)d_in[3];
    const float* bk = (const float*)d_in[4];
    const float* Wv = (const float*)d_in[5];
    const float* bv = (const float*)d_in[6];

    float* out0  = (float*)d_out;                          // [S,B,HID] = 262144
    float* probs = out0 + (size_t)S_ * B_ * HID_;          // [B,NH,S,S] = 1048576

    float* ws       = (float*)d_ws;
    float* ws_qkv   = ws;                                  // mx -> ql|kl|vl : 3*262144 floats
    float* ws_gamma = ws + (size_t)3 * BSH;                // 4096 floats, flat chunk order
    float* ws_lc    = ws + (size_t)3 * BSH + 4096;         // 131072 floats (NO alias: attn
                                                           // writes lc while other blocks read ql)

    gemm3_fused_kernel<<<dim3(384), dim3(256), 0, stream>>>(query, Wq, Wk, Wv, ws_qkv);
    mobius_rows_kernel<<<dim3(384), dim3(256), 0, stream>>>(query, bq, bk, bv, ws_qkv, ws_gamma);
    attn_kernel<<<dim3(512), dim3(256), 0, stream>>>(ws_qkv, ws_gamma, probs, ws_lc);
    outproj_kernel<<<dim3(B_ * S_), dim3(256), 0, stream>>>(ws_lc, out0);
}